// Round 2
// baseline (766.666 us; speedup 1.0000x reference)
//
#include <hip/hip_runtime.h>
#include <hip/hip_bf16.h>

// Problem constants (reference: T=64, S=1024, D=2048)
#define T_DIM 64
#define S_DIM 1024
#define D_DIM 2048

// 1/sqrt(2048)
#define INV_NORM 0.022097086912079608f

// ---------------------------------------------------------------------------
// Kernel A: phi = exp((eps @ chol + nu) / sqrt(D))
//   chol = tril(Psi,-1) + I  -> B[i][j] = (i>j) ? Psi[i][j] : (i==j ? 1 : 0)
//   Triangular: B[i][j]==0 for i<j, so K-loop starts at k0 = col0.
//   64x64 output tile, BK=16, 256 threads, 4x4 micro-tile per thread.
//   fp32 on vector ALU (no fp32 MFMA on CDNA4).
// ---------------------------------------------------------------------------
__global__ __launch_bounds__(256) void gemm_phi_kernel(
    const float* __restrict__ eps,   // [S, D]
    const float* __restrict__ Psi,   // [D, D]
    const float* __restrict__ nu,    // [D]
    float* __restrict__ phi)         // [S, D] (output slot)
{
    __shared__ float As[16][68];   // As[k][m], padded stride 68
    __shared__ float Bs[16][68];   // Bs[k][n]

    const int bn = blockIdx.x;       // D / 64  (output cols)
    const int bm = blockIdx.y;       // S / 64  (output rows)
    const int tid = threadIdx.x;     // 0..255
    const int tx = tid & 15;         // 0..15 -> output col group
    const int ty = tid >> 4;         // 0..15 -> output row group
    const int row0 = bm * 64;
    const int col0 = bn * 64;

    // A staging: thread loads float4 of eps at (row = tid>>2, k = (tid&3)*4)
    const int a_row = tid >> 2;        // 0..63
    const int a_k   = (tid & 3) * 4;   // 0,4,8,12
    // B staging: thread loads float4 of Psi at (k = tid>>4, j = (tid&15)*4)
    const int b_k = tid >> 4;          // 0..15
    const int b_j = (tid & 15) * 4;    // 0..60

    float c[4][4] = {};

    for (int k0 = col0; k0 < D_DIM; k0 += 16) {
        // ---- global loads into registers ----
        const float4 av = *(const float4*)&eps[(size_t)(row0 + a_row) * D_DIM + k0 + a_k];

        const int gi = k0 + b_k;
        const int gj = col0 + b_j;
        const float4 bv = *(const float4*)&Psi[(size_t)gi * D_DIM + gj];
        float b0 = (gi > gj    ) ? bv.x : ((gi == gj    ) ? 1.0f : 0.0f);
        float b1 = (gi > gj + 1) ? bv.y : ((gi == gj + 1) ? 1.0f : 0.0f);
        float b2 = (gi > gj + 2) ? bv.z : ((gi == gj + 2) ? 1.0f : 0.0f);
        float b3 = (gi > gj + 3) ? bv.w : ((gi == gj + 3) ? 1.0f : 0.0f);

        __syncthreads();   // previous iteration's compute done before overwrite

        // A stored transposed: As[k][m]
        As[a_k + 0][a_row] = av.x;
        As[a_k + 1][a_row] = av.y;
        As[a_k + 2][a_row] = av.z;
        As[a_k + 3][a_row] = av.w;
        *(float4*)&Bs[b_k][b_j] = make_float4(b0, b1, b2, b3);

        __syncthreads();

        #pragma unroll
        for (int kk = 0; kk < 16; ++kk) {
            const float4 a4 = *(const float4*)&As[kk][ty * 4];
            const float4 b4 = *(const float4*)&Bs[kk][tx * 4];
            const float ar[4] = {a4.x, a4.y, a4.z, a4.w};
            const float br[4] = {b4.x, b4.y, b4.z, b4.w};
            #pragma unroll
            for (int i = 0; i < 4; ++i)
                #pragma unroll
                for (int j = 0; j < 4; ++j)
                    c[i][j] = fmaf(ar[i], br[j], c[i][j]);
        }
    }

    // ---- epilogue: phi = exp((c + nu) * INV_NORM) ----
    const float4 nu4 = *(const float4*)&nu[col0 + tx * 4];
    #pragma unroll
    for (int i = 0; i < 4; ++i) {
        const int s = row0 + ty * 4 + i;
        float4 o;
        o.x = expf((c[i][0] + nu4.x) * INV_NORM);
        o.y = expf((c[i][1] + nu4.y) * INV_NORM);
        o.z = expf((c[i][2] + nu4.z) * INV_NORM);
        o.w = expf((c[i][3] + nu4.w) * INV_NORM);
        *(float4*)&phi[(size_t)s * D_DIM + col0 + tx * 4] = o;
    }
}

// ---------------------------------------------------------------------------
// Kernel B: per-row stats.  row_sq[s] = sum(phi[s,:]^2), x0phi[s] = phi[s,:]@x_0
// One block (256 threads) per row s.
// ---------------------------------------------------------------------------
__global__ __launch_bounds__(256) void row_stats_kernel(
    const float* __restrict__ phi,   // [S, D]
    const float* __restrict__ x0,    // [D]
    float* __restrict__ row_sq,      // [S]
    float* __restrict__ x0phi)       // [S]
{
    const int s = blockIdx.x;
    const int tid = threadIdx.x;

    float sq = 0.0f, xp = 0.0f;
    #pragma unroll
    for (int base = 0; base < D_DIM; base += 1024) {
        const int d = base + tid * 4;
        const float4 p = *(const float4*)&phi[(size_t)s * D_DIM + d];
        const float4 x = *(const float4*)&x0[d];
        sq += p.x * p.x + p.y * p.y + p.z * p.z + p.w * p.w;
        xp += p.x * x.x + p.y * x.y + p.z * x.z + p.w * x.w;
    }

    // wave (64-lane) butterfly reduction
    #pragma unroll
    for (int off = 32; off > 0; off >>= 1) {
        sq += __shfl_down(sq, off);
        xp += __shfl_down(xp, off);
    }

    __shared__ float ssq[4];
    __shared__ float sxp[4];
    if ((tid & 63) == 0) {
        ssq[tid >> 6] = sq;
        sxp[tid >> 6] = xp;
    }
    __syncthreads();
    if (tid == 0) {
        row_sq[s] = ssq[0] + ssq[1] + ssq[2] + ssq[3];
        x0phi[s]  = sxp[0] + sxp[1] + sxp[2] + sxp[3];
    }
}

// ---------------------------------------------------------------------------
// Kernel C: decode + streaming write.
//   x_t_pred[t,s,d] = exp(-time[t]*sigma_s) * (x0phi_s / sigma_s) * phi[s,d]
//   x0xt_pred[t,s]  = (exp(-time[t]*sigma_s) * x0phi_s)^2 / sigma_s
//     (diag of x_t_pred @ phi.T collapses algebraically: sum_d fea*phi =
//      w*row_sq = x0phi, so diag[t,s] = exp_decay*x0phi — no second einsum.)
// One block per s; phi row held in registers; loop over t (537 MB of stores).
// ---------------------------------------------------------------------------
__global__ __launch_bounds__(256) void decode_kernel(
    const float* __restrict__ phi,     // [S, D]
    const float* __restrict__ time,    // [T]
    const float* __restrict__ row_sq,  // [S]
    const float* __restrict__ x0phi,   // [S]
    float* __restrict__ x_t,           // [T, S, D]
    float* __restrict__ x0xt)          // [T, S]
{
    const int s = blockIdx.x;
    const int tid = threadIdx.x;

    __shared__ float st[T_DIM];
    if (tid < T_DIM) st[tid] = time[tid];

    const float sigma = row_sq[s];
    const float xp = x0phi[s];
    const float w = xp / sigma;

    // phi row: 8 floats/thread (two float4 at d = tid*4 and d = 1024 + tid*4)
    const float4 p0 = *(const float4*)&phi[(size_t)s * D_DIM + tid * 4];
    const float4 p1 = *(const float4*)&phi[(size_t)s * D_DIM + 1024 + tid * 4];
    float4 f0, f1;
    f0.x = w * p0.x; f0.y = w * p0.y; f0.z = w * p0.z; f0.w = w * p0.w;
    f1.x = w * p1.x; f1.y = w * p1.y; f1.z = w * p1.z; f1.w = w * p1.w;

    __syncthreads();

    #pragma unroll 4
    for (int t = 0; t < T_DIM; ++t) {
        const float e = expf(-st[t] * sigma);   // BETA = 1
        float4 o0, o1;
        o0.x = e * f0.x; o0.y = e * f0.y; o0.z = e * f0.z; o0.w = e * f0.w;
        o1.x = e * f1.x; o1.y = e * f1.y; o1.z = e * f1.z; o1.w = e * f1.w;
        float* dst = &x_t[((size_t)t * S_DIM + s) * D_DIM];
        *(float4*)&dst[tid * 4] = o0;
        *(float4*)&dst[1024 + tid * 4] = o1;
    }

    if (tid < T_DIM) {
        const float e = expf(-st[tid] * sigma);
        const float diag = e * xp;
        x0xt[(size_t)tid * S_DIM + s] = diag * diag / sigma;
    }
}

// ---------------------------------------------------------------------------
// Launch
// ---------------------------------------------------------------------------
extern "C" void kernel_launch(void* const* d_in, const int* in_sizes, int n_in,
                              void* d_out, int out_size, void* d_ws, size_t ws_size,
                              hipStream_t stream) {
    const float* time = (const float*)d_in[0];   // [T]
    const float* x0   = (const float*)d_in[1];   // [D,1]
    const float* nu   = (const float*)d_in[2];   // [D]
    const float* Psi  = (const float*)d_in[3];   // [D,D]
    const float* eps  = (const float*)d_in[4];   // [S,D]

    float* out = (float*)d_out;
    float* x_t  = out;                                        // T*S*D
    float* x0xt = out + (size_t)T_DIM * S_DIM * D_DIM;        // T*S
    float* phi  = x0xt + (size_t)T_DIM * S_DIM;               // S*D

    float* row_sq = (float*)d_ws;        // [S]
    float* x0phi  = row_sq + S_DIM;      // [S]

    dim3 gemm_grid(D_DIM / 64, S_DIM / 64);   // (32, 16)
    gemm_phi_kernel<<<gemm_grid, 256, 0, stream>>>(eps, Psi, nu, phi);
    row_stats_kernel<<<S_DIM, 256, 0, stream>>>(phi, x0, row_sq, x0phi);
    decode_kernel<<<S_DIM, 256, 0, stream>>>(phi, time, row_sq, x0phi, x_t, x0xt);
}

// Round 10
// 699.971 us; speedup vs baseline: 1.0953x; 1.0953x over previous
//
#include <hip/hip_runtime.h>
#include <hip/hip_bf16.h>

// Problem constants (reference: T=64, S=1024, D=2048)
#define T_DIM 64
#define S_DIM 1024
#define D_DIM 2048

// 1/sqrt(2048)
#define INV_NORM 0.022097086912079608f

typedef __attribute__((ext_vector_type(8))) short     bf16x8;  // MFMA A/B frag (4 VGPR)
typedef __attribute__((ext_vector_type(4))) float     f32x4;   // MFMA C/D frag
typedef __attribute__((ext_vector_type(8))) unsigned short u16x8;
typedef __attribute__((ext_vector_type(4))) unsigned short u16x4;

static __device__ inline unsigned short f2bf(float x) {
    __hip_bfloat16 b = __float2bfloat16(x);
    return *reinterpret_cast<unsigned short*>(&b);
}
static __device__ inline float bf2f(unsigned short u) {
    __hip_bfloat16 b = *reinterpret_cast<__hip_bfloat16*>(&u);
    return __bfloat162float(b);
}
static __device__ inline void split2(float x, unsigned short& h, unsigned short& l) {
    h = f2bf(x);
    l = f2bf(x - bf2f(h));
}

// ---------------------------------------------------------------------------
// Prep 1: split eps (fp32 [S,D]) into bf16 hi/lo planes (row-major, same layout)
// ---------------------------------------------------------------------------
__global__ __launch_bounds__(256) void prep_eps_kernel(
    const float* __restrict__ eps,
    unsigned short* __restrict__ Ah, unsigned short* __restrict__ Al)
{
    const int idx = (blockIdx.x * 256 + threadIdx.x) * 4;   // float4 granularity
    const float4 v = *(const float4*)&eps[idx];
    u16x4 h, l;
    unsigned short* hp = (unsigned short*)&h;
    unsigned short* lp = (unsigned short*)&l;
    split2(v.x, hp[0], lp[0]);
    split2(v.y, hp[1], lp[1]);
    split2(v.z, hp[2], lp[2]);
    split2(v.w, hp[3], lp[3]);
    *(u16x4*)&Ah[idx] = h;
    *(u16x4*)&Al[idx] = l;
}

// ---------------------------------------------------------------------------
// Prep 2: chol mask + TRANSPOSE + split.
//   chol[k][n] = (k>n) ? Psi[k][n] : (k==n ? 1 : 0)
//   Output Bt_hi/lo[n][k] = bf16 split of chol[k][n]   (so MFMA B-frag reads
//   8 consecutive k per lane). 64x64 tiles via LDS.
// ---------------------------------------------------------------------------
__global__ __launch_bounds__(256) void prep_chol_kernel(
    const float* __restrict__ Psi,
    unsigned short* __restrict__ Bh, unsigned short* __restrict__ Bl)
{
    __shared__ float tile[64][65];
    const int k0 = blockIdx.x * 64;   // source row block (k)
    const int n0 = blockIdx.y * 64;   // source col block (n)
    const int tid = threadIdx.x;
    const int tr = tid >> 4;          // 0..15
    const int tc = (tid & 15) * 4;    // 0,4,..,60

    #pragma unroll
    for (int p = 0; p < 4; ++p) {
        const int r = p * 16 + tr;
        const float4 v = *(const float4*)&Psi[(size_t)(k0 + r) * D_DIM + n0 + tc];
        tile[r][tc + 0] = v.x;
        tile[r][tc + 1] = v.y;
        tile[r][tc + 2] = v.z;
        tile[r][tc + 3] = v.w;
    }
    __syncthreads();

    #pragma unroll
    for (int p = 0; p < 4; ++p) {
        const int nl = p * 16 + tr;        // local n (output row)
        const int kl = tc;                 // local k (output col)
        const int gn = n0 + nl;
        u16x4 h, l;
        unsigned short* hp = (unsigned short*)&h;
        unsigned short* lp = (unsigned short*)&l;
        #pragma unroll
        for (int i = 0; i < 4; ++i) {
            const int gk = k0 + kl + i;
            float v = tile[kl + i][nl];
            v = (gk > gn) ? v : ((gk == gn) ? 1.0f : 0.0f);
            split2(v, hp[i], lp[i]);
        }
        *(u16x4*)&Bh[(size_t)gn * D_DIM + k0 + kl] = h;
        *(u16x4*)&Bl[(size_t)gn * D_DIM + k0 + kl] = l;
    }
}

// ---------------------------------------------------------------------------
// Kernel A: phi = exp((eps @ chol + nu)/sqrt(D)) via split-bf16 MFMA.
//   C = A*Bt^T with A[m][k], Bt[n][k]; 3 products: ah*bh + ah*bl + al*bh.
//   128x128 tile, BK=32, 4 waves (2x2), each wave 64x64 = 4x4 frags 16x16x32.
//   LDS XOR-swizzle (byte ^= (row&3)<<4) -> residual read conflict ~4-way.
//   Triangular: K-loop starts at k0 = col0.
// ---------------------------------------------------------------------------
#define BM 128
#define BN 128
#define BK 32

__global__ __launch_bounds__(256) void gemm_mfma_kernel(
    const unsigned short* __restrict__ Ah, const unsigned short* __restrict__ Al,
    const unsigned short* __restrict__ Bh, const unsigned short* __restrict__ Bl,
    const float* __restrict__ nu, float* __restrict__ phi)
{
    __shared__ __align__(16) unsigned short sAh[BM * BK];
    __shared__ __align__(16) unsigned short sAl[BM * BK];
    __shared__ __align__(16) unsigned short sBh[BM * BK];
    __shared__ __align__(16) unsigned short sBl[BM * BK];

    const int tid = threadIdx.x;
    const int bn = blockIdx.x, bm = blockIdx.y;
    const int row0 = bm * BM, col0 = bn * BN;
    const int lane = tid & 63, w = tid >> 6;
    const int wr = w >> 1, wc = w & 1;

    // --- staging coords: thread stages row sr, 32B half sh of each array ---
    const int sr = tid >> 1;       // 0..127
    const int sh = tid & 1;        // 0..1
    const size_t gA = (size_t)(row0 + sr) * D_DIM;
    const size_t gB = (size_t)(col0 + sr) * D_DIM;
    const int swz = (sr & 3) << 4;
    const int ldsOff0 = sr * 64 + ((sh * 32 +  0) ^ swz);
    const int ldsOff1 = sr * 64 + ((sh * 32 + 16) ^ swz);
    const int eOff0 = sh * 16;       // element offsets of the two u16x8 chunks
    const int eOff1 = sh * 16 + 8;

    u16x8 rAh0, rAh1, rAl0, rAl1, rBh0, rBh1, rBl0, rBl1;

#define LOADG(k)  do {                                              \
        rAh0 = *(const u16x8*)&Ah[gA + (k) + eOff0];                \
        rAh1 = *(const u16x8*)&Ah[gA + (k) + eOff1];                \
        rAl0 = *(const u16x8*)&Al[gA + (k) + eOff0];                \
        rAl1 = *(const u16x8*)&Al[gA + (k) + eOff1];                \
        rBh0 = *(const u16x8*)&Bh[gB + (k) + eOff0];                \
        rBh1 = *(const u16x8*)&Bh[gB + (k) + eOff1];                \
        rBl0 = *(const u16x8*)&Bl[gB + (k) + eOff0];                \
        rBl1 = *(const u16x8*)&Bl[gB + (k) + eOff1];                \
    } while (0)

    f32x4 acc[4][4] = {};

    LOADG(col0);
    for (int k0 = col0; k0 < D_DIM; k0 += BK) {
        __syncthreads();   // previous iteration's LDS reads complete
        *(u16x8*)((char*)sAh + ldsOff0) = rAh0;
        *(u16x8*)((char*)sAh + ldsOff1) = rAh1;
        *(u16x8*)((char*)sAl + ldsOff0) = rAl0;
        *(u16x8*)((char*)sAl + ldsOff1) = rAl1;
        *(u16x8*)((char*)sBh + ldsOff0) = rBh0;
        *(u16x8*)((char*)sBh + ldsOff1) = rBh1;
        *(u16x8*)((char*)sBl + ldsOff0) = rBl0;
        *(u16x8*)((char*)sBl + ldsOff1) = rBl1;
        __syncthreads();

        if (k0 + BK < D_DIM) LOADG(k0 + BK);   // prefetch next tile (overlaps MFMA)

        bf16x8 ah[4], al[4], bh[4], bl[4];
        const int cb = (lane >> 4) * 16;       // k-group byte offset
        #pragma unroll
        for (int f = 0; f < 4; ++f) {
            const int rA = wr * 64 + f * 16 + (lane & 15);
            const int aoff = rA * 64 + (cb ^ ((rA & 3) << 4));
            ah[f] = *(const bf16x8*)((const char*)sAh + aoff);
            al[f] = *(const bf16x8*)((const char*)sAl + aoff);
            const int rB = wc * 64 + f * 16 + (lane & 15);
            const int boff = rB * 64 + (cb ^ ((rB & 3) << 4));
            bh[f] = *(const bf16x8*)((const char*)sBh + boff);
            bl[f] = *(const bf16x8*)((const char*)sBl + boff);
        }

        #pragma unroll
        for (int i = 0; i < 4; ++i)
            #pragma unroll
            for (int j = 0; j < 4; ++j) {
                acc[i][j] = __builtin_amdgcn_mfma_f32_16x16x32_bf16(ah[i], bh[j], acc[i][j], 0, 0, 0);
                acc[i][j] = __builtin_amdgcn_mfma_f32_16x16x32_bf16(ah[i], bl[j], acc[i][j], 0, 0, 0);
                acc[i][j] = __builtin_amdgcn_mfma_f32_16x16x32_bf16(al[i], bh[j], acc[i][j], 0, 0, 0);
            }
    }
#undef LOADG

    // --- epilogue: phi = exp((acc + nu)*INV_NORM) ---
    // C/D frag: col = lane&15, row = (lane>>4)*4 + reg   [m89-verified]
    #pragma unroll
    for (int j = 0; j < 4; ++j) {
        const int col = col0 + wc * 64 + j * 16 + (lane & 15);
        const float nuv = nu[col];
        #pragma unroll
        for (int i = 0; i < 4; ++i) {
            const int rbase = row0 + wr * 64 + i * 16 + (lane >> 4) * 4;
            #pragma unroll
            for (int r = 0; r < 4; ++r)
                phi[(size_t)(rbase + r) * D_DIM + col] =
                    expf((acc[i][j][r] + nuv) * INV_NORM);
        }
    }
}

// ---------------------------------------------------------------------------
// Kernel B: per-row stats.  row_sq[s] = sum(phi[s,:]^2), x0phi[s] = phi[s,:]@x_0
// ---------------------------------------------------------------------------
__global__ __launch_bounds__(256) void row_stats_kernel(
    const float* __restrict__ phi,
    const float* __restrict__ x0,
    float* __restrict__ row_sq,
    float* __restrict__ x0phi)
{
    const int s = blockIdx.x;
    const int tid = threadIdx.x;

    float sq = 0.0f, xp = 0.0f;
    #pragma unroll
    for (int base = 0; base < D_DIM; base += 1024) {
        const int d = base + tid * 4;
        const float4 p = *(const float4*)&phi[(size_t)s * D_DIM + d];
        const float4 x = *(const float4*)&x0[d];
        sq += p.x * p.x + p.y * p.y + p.z * p.z + p.w * p.w;
        xp += p.x * x.x + p.y * x.y + p.z * x.z + p.w * x.w;
    }

    #pragma unroll
    for (int off = 32; off > 0; off >>= 1) {
        sq += __shfl_down(sq, off);
        xp += __shfl_down(xp, off);
    }

    __shared__ float ssq[4];
    __shared__ float sxp[4];
    if ((tid & 63) == 0) {
        ssq[tid >> 6] = sq;
        sxp[tid >> 6] = xp;
    }
    __syncthreads();
    if (tid == 0) {
        row_sq[s] = ssq[0] + ssq[1] + ssq[2] + ssq[3];
        x0phi[s]  = sxp[0] + sxp[1] + sxp[2] + sxp[3];
    }
}

// ---------------------------------------------------------------------------
// Kernel C: decode + streaming write (537 MB stores — the HBM floor).
//   x_t_pred[t,s,d] = exp(-time[t]*sigma_s) * (x0phi_s/sigma_s) * phi[s,d]
//   x0xt_pred[t,s]  = (exp(-time[t]*sigma_s) * x0phi_s)^2 / sigma_s
//     (diag of x_t_pred @ phi.T collapses: sum_d fea*phi = w*row_sq = x0phi.)
// ---------------------------------------------------------------------------
__global__ __launch_bounds__(256) void decode_kernel(
    const float* __restrict__ phi,
    const float* __restrict__ time,
    const float* __restrict__ row_sq,
    const float* __restrict__ x0phi,
    float* __restrict__ x_t,
    float* __restrict__ x0xt)
{
    const int s = blockIdx.x;
    const int tid = threadIdx.x;

    __shared__ float st[T_DIM];
    if (tid < T_DIM) st[tid] = time[tid];

    const float sigma = row_sq[s];
    const float xp = x0phi[s];
    const float w = xp / sigma;

    const float4 p0 = *(const float4*)&phi[(size_t)s * D_DIM + tid * 4];
    const float4 p1 = *(const float4*)&phi[(size_t)s * D_DIM + 1024 + tid * 4];
    float4 f0, f1;
    f0.x = w * p0.x; f0.y = w * p0.y; f0.z = w * p0.z; f0.w = w * p0.w;
    f1.x = w * p1.x; f1.y = w * p1.y; f1.z = w * p1.z; f1.w = w * p1.w;

    __syncthreads();

    #pragma unroll 4
    for (int t = 0; t < T_DIM; ++t) {
        const float e = expf(-st[t] * sigma);   // BETA = 1
        float4 o0, o1;
        o0.x = e * f0.x; o0.y = e * f0.y; o0.z = e * f0.z; o0.w = e * f0.w;
        o1.x = e * f1.x; o1.y = e * f1.y; o1.z = e * f1.z; o1.w = e * f1.w;
        float* dst = &x_t[((size_t)t * S_DIM + s) * D_DIM];
        *(float4*)&dst[tid * 4] = o0;
        *(float4*)&dst[1024 + tid * 4] = o1;
    }

    if (tid < T_DIM) {
        const float e = expf(-st[tid] * sigma);
        const float diag = e * xp;
        x0xt[(size_t)tid * S_DIM + s] = diag * diag / sigma;
    }
}

// ---------------------------------------------------------------------------
// Launch
// ---------------------------------------------------------------------------
extern "C" void kernel_launch(void* const* d_in, const int* in_sizes, int n_in,
                              void* d_out, int out_size, void* d_ws, size_t ws_size,
                              hipStream_t stream) {
    const float* time = (const float*)d_in[0];   // [T]
    const float* x0   = (const float*)d_in[1];   // [D,1]
    const float* nu   = (const float*)d_in[2];   // [D]
    const float* Psi  = (const float*)d_in[3];   // [D,D]
    const float* eps  = (const float*)d_in[4];   // [S,D]

    float* out = (float*)d_out;
    float* x_t  = out;                                        // T*S*D
    float* x0xt = out + (size_t)T_DIM * S_DIM * D_DIM;        // T*S
    float* phi  = x0xt + (size_t)T_DIM * S_DIM;               // S*D

    // workspace layout (ushort planes, then f32 stats)
    unsigned short* Ah = (unsigned short*)d_ws;               // S*D
    unsigned short* Al = Ah + (size_t)S_DIM * D_DIM;          // S*D
    unsigned short* Bh = Al + (size_t)S_DIM * D_DIM;          // D*D
    unsigned short* Bl = Bh + (size_t)D_DIM * D_DIM;          // D*D
    float* row_sq = (float*)(Bl + (size_t)D_DIM * D_DIM);     // [S]
    float* x0phi  = row_sq + S_DIM;                           // [S]

    prep_eps_kernel<<<(S_DIM * D_DIM) / (256 * 4), 256, 0, stream>>>(eps, Ah, Al);
    prep_chol_kernel<<<dim3(D_DIM / 64, D_DIM / 64), 256, 0, stream>>>(Psi, Bh, Bl);
    gemm_mfma_kernel<<<dim3(D_DIM / BN, S_DIM / BM), 256, 0, stream>>>(Ah, Al, Bh, Bl, nu, phi);
    row_stats_kernel<<<S_DIM, 256, 0, stream>>>(phi, x0, row_sq, x0phi);
    decode_kernel<<<S_DIM, 256, 0, stream>>>(phi, time, row_sq, x0phi, x_t, x0xt);
}

// Round 16
// 634.530 us; speedup vs baseline: 1.2082x; 1.1031x over previous
//
#include <hip/hip_runtime.h>
#include <hip/hip_bf16.h>

// Problem constants (reference: T=64, S=1024, D=2048)
#define T_DIM 64
#define S_DIM 1024
#define D_DIM 2048

// 1/sqrt(2048)
#define INV_NORM 0.022097086912079608f

typedef __attribute__((ext_vector_type(8))) short     bf16x8;  // MFMA A/B frag (4 VGPR)
typedef __attribute__((ext_vector_type(4))) float     f32x4;   // MFMA C/D frag + NT stores
typedef __attribute__((ext_vector_type(8))) unsigned short u16x8;
typedef __attribute__((ext_vector_type(4))) unsigned short u16x4;

static __device__ inline unsigned short f2bf(float x) {
    __hip_bfloat16 b = __float2bfloat16(x);
    return *reinterpret_cast<unsigned short*>(&b);
}
static __device__ inline float bf2f(unsigned short u) {
    __hip_bfloat16 b = *reinterpret_cast<__hip_bfloat16*>(&u);
    return __bfloat162float(b);
}
static __device__ inline void split2(float x, unsigned short& h, unsigned short& l) {
    h = f2bf(x);
    l = f2bf(x - bf2f(h));
}

// ---------------------------------------------------------------------------
// Prep 1: split eps (fp32 [S,D]) into bf16 hi/lo planes (row-major, same layout)
// ---------------------------------------------------------------------------
__global__ __launch_bounds__(256) void prep_eps_kernel(
    const float* __restrict__ eps,
    unsigned short* __restrict__ Ah, unsigned short* __restrict__ Al)
{
    const int idx = (blockIdx.x * 256 + threadIdx.x) * 4;   // float4 granularity
    const float4 v = *(const float4*)&eps[idx];
    u16x4 h, l;
    unsigned short* hp = (unsigned short*)&h;
    unsigned short* lp = (unsigned short*)&l;
    split2(v.x, hp[0], lp[0]);
    split2(v.y, hp[1], lp[1]);
    split2(v.z, hp[2], lp[2]);
    split2(v.w, hp[3], lp[3]);
    *(u16x4*)&Ah[idx] = h;
    *(u16x4*)&Al[idx] = l;
}

// ---------------------------------------------------------------------------
// Prep 2: chol mask + TRANSPOSE + split.
//   chol[k][n] = (k>n) ? Psi[k][n] : (k==n ? 1 : 0)
//   Output Bt_hi/lo[n][k] = bf16 split of chol[k][n]. 64x64 tiles via LDS.
// ---------------------------------------------------------------------------
__global__ __launch_bounds__(256) void prep_chol_kernel(
    const float* __restrict__ Psi,
    unsigned short* __restrict__ Bh, unsigned short* __restrict__ Bl)
{
    __shared__ float tile[64][65];
    const int k0 = blockIdx.x * 64;   // source row block (k)
    const int n0 = blockIdx.y * 64;   // source col block (n)
    const int tid = threadIdx.x;
    const int tr = tid >> 4;          // 0..15
    const int tc = (tid & 15) * 4;    // 0,4,..,60

    #pragma unroll
    for (int p = 0; p < 4; ++p) {
        const int r = p * 16 + tr;
        const float4 v = *(const float4*)&Psi[(size_t)(k0 + r) * D_DIM + n0 + tc];
        tile[r][tc + 0] = v.x;
        tile[r][tc + 1] = v.y;
        tile[r][tc + 2] = v.z;
        tile[r][tc + 3] = v.w;
    }
    __syncthreads();

    #pragma unroll
    for (int p = 0; p < 4; ++p) {
        const int nl = p * 16 + tr;        // local n (output row)
        const int kl = tc;                 // local k (output col)
        const int gn = n0 + nl;
        u16x4 h, l;
        unsigned short* hp = (unsigned short*)&h;
        unsigned short* lp = (unsigned short*)&l;
        #pragma unroll
        for (int i = 0; i < 4; ++i) {
            const int gk = k0 + kl + i;
            float v = tile[kl + i][nl];
            v = (gk > gn) ? v : ((gk == gn) ? 1.0f : 0.0f);
            split2(v, hp[i], lp[i]);
        }
        *(u16x4*)&Bh[(size_t)gn * D_DIM + k0 + kl] = h;
        *(u16x4*)&Bl[(size_t)gn * D_DIM + k0 + kl] = l;
    }
}

// ---------------------------------------------------------------------------
// Kernel A: phi = exp((eps @ chol + nu)/sqrt(D)) via split-bf16 MFMA.
//   (UNCHANGED — isolating the decode variable.)
// ---------------------------------------------------------------------------
#define BM 128
#define BN 128
#define BK 32

__global__ __launch_bounds__(256) void gemm_mfma_kernel(
    const unsigned short* __restrict__ Ah, const unsigned short* __restrict__ Al,
    const unsigned short* __restrict__ Bh, const unsigned short* __restrict__ Bl,
    const float* __restrict__ nu, float* __restrict__ phi)
{
    __shared__ __align__(16) unsigned short sAh[BM * BK];
    __shared__ __align__(16) unsigned short sAl[BM * BK];
    __shared__ __align__(16) unsigned short sBh[BM * BK];
    __shared__ __align__(16) unsigned short sBl[BM * BK];

    const int tid = threadIdx.x;
    const int bn = blockIdx.x, bm = blockIdx.y;
    const int row0 = bm * BM, col0 = bn * BN;
    const int lane = tid & 63, w = tid >> 6;
    const int wr = w >> 1, wc = w & 1;

    const int sr = tid >> 1;       // 0..127
    const int sh = tid & 1;        // 0..1
    const size_t gA = (size_t)(row0 + sr) * D_DIM;
    const size_t gB = (size_t)(col0 + sr) * D_DIM;
    const int swz = (sr & 3) << 4;
    const int ldsOff0 = sr * 64 + ((sh * 32 +  0) ^ swz);
    const int ldsOff1 = sr * 64 + ((sh * 32 + 16) ^ swz);
    const int eOff0 = sh * 16;
    const int eOff1 = sh * 16 + 8;

    u16x8 rAh0, rAh1, rAl0, rAl1, rBh0, rBh1, rBl0, rBl1;

#define LOADG(k)  do {                                              \
        rAh0 = *(const u16x8*)&Ah[gA + (k) + eOff0];                \
        rAh1 = *(const u16x8*)&Ah[gA + (k) + eOff1];                \
        rAl0 = *(const u16x8*)&Al[gA + (k) + eOff0];                \
        rAl1 = *(const u16x8*)&Al[gA + (k) + eOff1];                \
        rBh0 = *(const u16x8*)&Bh[gB + (k) + eOff0];                \
        rBh1 = *(const u16x8*)&Bh[gB + (k) + eOff1];                \
        rBl0 = *(const u16x8*)&Bl[gB + (k) + eOff0];                \
        rBl1 = *(const u16x8*)&Bl[gB + (k) + eOff1];                \
    } while (0)

    f32x4 acc[4][4] = {};

    LOADG(col0);
    for (int k0 = col0; k0 < D_DIM; k0 += BK) {
        __syncthreads();
        *(u16x8*)((char*)sAh + ldsOff0) = rAh0;
        *(u16x8*)((char*)sAh + ldsOff1) = rAh1;
        *(u16x8*)((char*)sAl + ldsOff0) = rAl0;
        *(u16x8*)((char*)sAl + ldsOff1) = rAl1;
        *(u16x8*)((char*)sBh + ldsOff0) = rBh0;
        *(u16x8*)((char*)sBh + ldsOff1) = rBh1;
        *(u16x8*)((char*)sBl + ldsOff0) = rBl0;
        *(u16x8*)((char*)sBl + ldsOff1) = rBl1;
        __syncthreads();

        if (k0 + BK < D_DIM) LOADG(k0 + BK);   // prefetch next tile

        bf16x8 ah[4], al[4], bh[4], bl[4];
        const int cb = (lane >> 4) * 16;
        #pragma unroll
        for (int f = 0; f < 4; ++f) {
            const int rA = wr * 64 + f * 16 + (lane & 15);
            const int aoff = rA * 64 + (cb ^ ((rA & 3) << 4));
            ah[f] = *(const bf16x8*)((const char*)sAh + aoff);
            al[f] = *(const bf16x8*)((const char*)sAl + aoff);
            const int rB = wc * 64 + f * 16 + (lane & 15);
            const int boff = rB * 64 + (cb ^ ((rB & 3) << 4));
            bh[f] = *(const bf16x8*)((const char*)sBh + boff);
            bl[f] = *(const bf16x8*)((const char*)sBl + boff);
        }

        #pragma unroll
        for (int i = 0; i < 4; ++i)
            #pragma unroll
            for (int j = 0; j < 4; ++j) {
                acc[i][j] = __builtin_amdgcn_mfma_f32_16x16x32_bf16(ah[i], bh[j], acc[i][j], 0, 0, 0);
                acc[i][j] = __builtin_amdgcn_mfma_f32_16x16x32_bf16(ah[i], bl[j], acc[i][j], 0, 0, 0);
                acc[i][j] = __builtin_amdgcn_mfma_f32_16x16x32_bf16(al[i], bh[j], acc[i][j], 0, 0, 0);
            }
    }
#undef LOADG

    // C/D frag: col = lane&15, row = (lane>>4)*4 + reg   [m89-verified]
    #pragma unroll
    for (int j = 0; j < 4; ++j) {
        const int col = col0 + wc * 64 + j * 16 + (lane & 15);
        const float nuv = nu[col];
        #pragma unroll
        for (int i = 0; i < 4; ++i) {
            const int rbase = row0 + wr * 64 + i * 16 + (lane >> 4) * 4;
            #pragma unroll
            for (int r = 0; r < 4; ++r)
                phi[(size_t)(rbase + r) * D_DIM + col] =
                    expf((acc[i][j][r] + nuv) * INV_NORM);
        }
    }
}

// ---------------------------------------------------------------------------
// Kernel B: per-row stats.  row_sq[s] = sum(phi[s,:]^2), x0phi[s] = phi[s,:]@x_0
// ---------------------------------------------------------------------------
__global__ __launch_bounds__(256) void row_stats_kernel(
    const float* __restrict__ phi,
    const float* __restrict__ x0,
    float* __restrict__ row_sq,
    float* __restrict__ x0phi)
{
    const int s = blockIdx.x;
    const int tid = threadIdx.x;

    float sq = 0.0f, xp = 0.0f;
    #pragma unroll
    for (int base = 0; base < D_DIM; base += 1024) {
        const int d = base + tid * 4;
        const float4 p = *(const float4*)&phi[(size_t)s * D_DIM + d];
        const float4 x = *(const float4*)&x0[d];
        sq += p.x * p.x + p.y * p.y + p.z * p.z + p.w * p.w;
        xp += p.x * x.x + p.y * x.y + p.z * x.z + p.w * x.w;
    }

    #pragma unroll
    for (int off = 32; off > 0; off >>= 1) {
        sq += __shfl_down(sq, off);
        xp += __shfl_down(xp, off);
    }

    __shared__ float ssq[4];
    __shared__ float sxp[4];
    if ((tid & 63) == 0) {
        ssq[tid >> 6] = sq;
        sxp[tid >> 6] = xp;
    }
    __syncthreads();
    if (tid == 0) {
        row_sq[s] = ssq[0] + ssq[1] + ssq[2] + ssq[3];
        x0phi[s]  = sxp[0] + sxp[1] + sxp[2] + sxp[3];
    }
}

// ---------------------------------------------------------------------------
// Kernel C v2: decode, t-split for TLP.
//   grid (S, T/8): block (s, ty) writes t = ty*8 .. ty*8+7.
//   8192 blocks (32/CU) vs 1024 (4/CU) before — 8x the store-latency hiding.
//   Nontemporal stores via ext_vector f32x4 (clang vector type — the HIP
//   float4 class is rejected by __builtin_nontemporal_store).
//   No LDS, no barrier.
// ---------------------------------------------------------------------------
#define T_PER_BLK 8

__global__ __launch_bounds__(256) void decode_kernel(
    const float* __restrict__ phi,
    const float* __restrict__ time,
    const float* __restrict__ row_sq,
    const float* __restrict__ x0phi,
    float* __restrict__ x_t,
    float* __restrict__ x0xt)
{
    const int s  = blockIdx.x;
    const int t0 = blockIdx.y * T_PER_BLK;
    const int tid = threadIdx.x;

    const float sigma = row_sq[s];
    const float xp = x0phi[s];
    const float w = xp / sigma;

    // phi row: 8 floats/thread (two f32x4 at d = tid*4 and d = 1024 + tid*4)
    const f32x4 p0 = *(const f32x4*)&phi[(size_t)s * D_DIM + tid * 4];
    const f32x4 p1 = *(const f32x4*)&phi[(size_t)s * D_DIM + 1024 + tid * 4];
    const f32x4 f0 = p0 * w;
    const f32x4 f1 = p1 * w;

    #pragma unroll
    for (int tt = 0; tt < T_PER_BLK; ++tt) {
        const int t = t0 + tt;
        const float e = expf(-time[t] * sigma);   // BETA = 1
        const f32x4 o0 = f0 * e;
        const f32x4 o1 = f1 * e;
        float* dst = &x_t[((size_t)t * S_DIM + s) * D_DIM];
        __builtin_nontemporal_store(o0, (f32x4*)&dst[tid * 4]);
        __builtin_nontemporal_store(o1, (f32x4*)&dst[1024 + tid * 4]);
    }

    if (tid < T_PER_BLK) {
        const int t = t0 + tid;
        const float e = expf(-time[t] * sigma);
        const float diag = e * xp;
        x0xt[(size_t)t * S_DIM + s] = diag * diag / sigma;
    }
}

// ---------------------------------------------------------------------------
// Launch
// ---------------------------------------------------------------------------
extern "C" void kernel_launch(void* const* d_in, const int* in_sizes, int n_in,
                              void* d_out, int out_size, void* d_ws, size_t ws_size,
                              hipStream_t stream) {
    const float* time = (const float*)d_in[0];   // [T]
    const float* x0   = (const float*)d_in[1];   // [D,1]
    const float* nu   = (const float*)d_in[2];   // [D]
    const float* Psi  = (const float*)d_in[3];   // [D,D]
    const float* eps  = (const float*)d_in[4];   // [S,D]

    float* out = (float*)d_out;
    float* x_t  = out;                                        // T*S*D
    float* x0xt = out + (size_t)T_DIM * S_DIM * D_DIM;        // T*S
    float* phi  = x0xt + (size_t)T_DIM * S_DIM;               // S*D

    // workspace layout (ushort planes, then f32 stats)
    unsigned short* Ah = (unsigned short*)d_ws;               // S*D
    unsigned short* Al = Ah + (size_t)S_DIM * D_DIM;          // S*D
    unsigned short* Bh = Al + (size_t)S_DIM * D_DIM;          // D*D
    unsigned short* Bl = Bh + (size_t)D_DIM * D_DIM;          // D*D
    float* row_sq = (float*)(Bl + (size_t)D_DIM * D_DIM);     // [S]
    float* x0phi  = row_sq + S_DIM;                           // [S]

    prep_eps_kernel<<<(S_DIM * D_DIM) / (256 * 4), 256, 0, stream>>>(eps, Ah, Al);
    prep_chol_kernel<<<dim3(D_DIM / 64, D_DIM / 64), 256, 0, stream>>>(Psi, Bh, Bl);
    gemm_mfma_kernel<<<dim3(D_DIM / BN, S_DIM / BM), 256, 0, stream>>>(Ah, Al, Bh, Bl, nu, phi);
    row_stats_kernel<<<S_DIM, 256, 0, stream>>>(phi, x0, row_sq, x0phi);
    decode_kernel<<<dim3(S_DIM, T_DIM / T_PER_BLK), 256, 0, stream>>>(phi, time, row_sq, x0phi, x_t, x0xt);
}